// Round 5
// baseline (249.668 us; speedup 1.0000x reference)
//
#include <hip/hip_runtime.h>
#include <math.h>

#define TOKENS 16384
#define HID    4096
#define NEXP   64
#define TOPK   8
#define KSPLIT 4                 // K-quarters, one per wave
#define WK     (HID / KSPLIT)    // 1024 k per wave
#define NSTEP  (WK / 32)         // 32 MFMA k-steps per wave
#define TAU    5e-4f
#define REFINE_BLOCKS 1024

typedef short          bf16x8 __attribute__((ext_vector_type(8)));
typedef unsigned short u16x8  __attribute__((ext_vector_type(8)));
typedef float          f32x4  __attribute__((ext_vector_type(4)));

__device__ __forceinline__ unsigned short bf16_rtn(float x) {
    unsigned u = __builtin_bit_cast(unsigned, x);
    u += 0x7FFFu + ((u >> 16) & 1u);
    return (unsigned short)(u >> 16);
}

__device__ __forceinline__ void splitf(float x, unsigned short& h, unsigned short& l) {
    h = bf16_rtn(x);
    float hf = __builtin_bit_cast(float, (unsigned)h << 16);
    l = bf16_rtn(x - hf);   // residual <= 2^-18 |x| after hi+lo
}

// ---------- prep: W fp32 -> bf16 hi/lo in ws, zero flag counter -------------
__global__ __launch_bounds__(256) void prep_kernel(
    const float* __restrict__ w,
    unsigned short* __restrict__ whi,
    unsigned short* __restrict__ wlo,
    int* __restrict__ flag_cnt)
{
    if (blockIdx.x == 0 && threadIdx.x == 0) flag_cnt[0] = 0;
    int gid = blockIdx.x * 256 + threadIdx.x;      // 128 blocks: 32768 threads x 8 elems
    const f32x4* wp = (const f32x4*)w;
    f32x4 v0 = wp[gid * 2 + 0];
    f32x4 v1 = wp[gid * 2 + 1];
    u16x8 h8, l8;
    #pragma unroll
    for (int j = 0; j < 8; ++j) {
        float x = (j < 4) ? v0[j] : v1[j - 4];
        unsigned short h, l;
        splitf(x, h, l);
        h8[j] = h; l8[j] = l;
    }
    *(u16x8*)(whi + (size_t)gid * 8) = h8;
    *(u16x8*)(wlo + (size_t)gid * 8) = l8;
}

// ---------- pass 1: barrier-free per-wave MFMA GEMM + top-8 -----------------
// Each wave: 16 tokens x 64 experts x K-quarter. A from HBM (fp32->split in
// reg), B direct bf16 frags from pre-converted ws (L2-resident). No LDS in
// the K loop; one barrier pair for the partial combine + top-k epilogue.
// Pipeline discipline: a circular-buffer slot is CONSUMED (CONVA) before the
// refill load targeting the same slot is issued (round-4 bug: LA-before-CONVA
// paired A step t+4 with B step t).
__global__ __launch_bounds__(256) void moe_gate_pass1(
    const float* __restrict__ hs,
    const unsigned short* __restrict__ whi,
    const unsigned short* __restrict__ wlo,
    float* __restrict__ out_idx_f,
    float* __restrict__ out_gate,
    int* __restrict__ flag_cnt,
    int* __restrict__ flag_list,
    int flag_cap)
{
    __shared__ float part[KSPLIT][16][68];   // 17.4 KB

    const int tid  = threadIdx.x;
    const int lane = tid & 63;
    const int wv   = tid >> 6;               // K-quarter index
    const int t0   = blockIdx.x * 16;
    const int row  = lane & 15;              // A-row / B-col within frag
    const int kg   = (lane >> 4) * 8;        // k sub-chunk (8 contiguous)
    const size_t kbase = (size_t)wv * WK;

    const float*          ap  = hs  + (size_t)(t0 + row) * HID + kbase + kg;
    const unsigned short* bhp = whi + (size_t)row * HID + kbase + kg;
    const unsigned short* blp = wlo + (size_t)row * HID + kbase + kg;

    f32x4  acc[4];
    #pragma unroll
    for (int ng = 0; ng < 4; ++ng) { acc[ng][0]=0.f; acc[ng][1]=0.f; acc[ng][2]=0.f; acc[ng][3]=0.f; }

    f32x4  Aq[4][2];           // A fp32 stage, depth 4
    bf16x8 Bh[2][4], Bl[2][4]; // B frags, depth 2
    bf16x8 fah, fal;

#define LA(s, t) { const f32x4* p = (const f32x4*)(ap + (t) * 32); \
                   Aq[s][0] = p[0]; Aq[s][1] = p[1]; }
#define LB(s, t) { _Pragma("unroll") for (int ng = 0; ng < 4; ++ng) { \
                     Bh[s][ng] = *(const bf16x8*)(bhp + ng * 16 * HID + (t) * 32); \
                     Bl[s][ng] = *(const bf16x8*)(blp + ng * 16 * HID + (t) * 32); } }
#define CONVA(s) { _Pragma("unroll") for (int j = 0; j < 8; ++j) { \
                     float x = (j < 4) ? Aq[s][0][j] : Aq[s][1][j - 4]; \
                     unsigned short h, l; splitf(x, h, l); \
                     fah[j] = (short)h; fal[j] = (short)l; } }
#define MF(bs) { _Pragma("unroll") for (int ng = 0; ng < 4; ++ng) { \
                   acc[ng] = __builtin_amdgcn_mfma_f32_16x16x32_bf16(fah, Bh[bs][ng], acc[ng], 0, 0, 0); \
                   acc[ng] = __builtin_amdgcn_mfma_f32_16x16x32_bf16(fah, Bl[bs][ng], acc[ng], 0, 0, 0); \
                   acc[ng] = __builtin_amdgcn_mfma_f32_16x16x32_bf16(fal, Bh[bs][ng], acc[ng], 0, 0, 0); } }

    LA(0, 0) LA(1, 1) LA(2, 2) LA(3, 3)
    LB(0, 0)

    #pragma unroll 4
    for (int t = 0; t < NSTEP - 4; ++t) {     // 28 iters
        CONVA(t & 3)                          // consume step t FIRST
        LA((t + 4) & 3, t + 4)                // then refill the slot (step t+4)
        LB((t + 1) & 1, t + 1)                // B one step ahead (L2-resident)
        MF(t & 1)
    }
    // t = 28..31 epilogue (A loads done; B loads for 29..31)
    LB(1, 29) CONVA(0) MF(0)
    LB(0, 30) CONVA(1) MF(1)
    LB(1, 31) CONVA(2) MF(0)
              CONVA(3) MF(1)

#undef LA
#undef LB
#undef CONVA
#undef MF

    // ---- combine K-partials + top-k ----
    #pragma unroll
    for (int ng = 0; ng < 4; ++ng)
        #pragma unroll
        for (int r = 0; r < 4; ++r)
            part[wv][(lane >> 4) * 4 + r][ng * 16 + (lane & 15)] = acc[ng][r];
    __syncthreads();

    for (int s = tid; s < 16 * 64; s += 256) {
        int tt = s >> 6, e = s & 63;
        float v = part[0][tt][e] + part[1][tt][e] + part[2][tt][e] + part[3][tt][e];
        part[0][tt][e] = v;
    }
    __syncthreads();

    if (tid < 16) {
        const int t = tid;
        float v[9];
        int   id[9];
        #pragma unroll
        for (int j = 0; j < 9; ++j) { v[j] = -INFINITY; id[j] = -1; }
        for (int e = 0; e < NEXP; ++e) {
            float x = part[0][t][e];
            if (x > v[8]) {
                int p = 8;
                while (p > 0 && v[p - 1] < x) {
                    v[p]  = v[p - 1];
                    id[p] = id[p - 1];
                    --p;
                }
                v[p]  = x;
                id[p] = e;
            }
        }
        float g = v[0] - v[1];
        #pragma unroll
        for (int j = 1; j < 8; ++j) g = fminf(g, v[j] - v[j + 1]);

        bool deferred = false;
        if (g < TAU) {
            int slot = atomicAdd(flag_cnt, 1);
            if (slot < flag_cap) {
                flag_list[slot] = t0 + t;
                deferred = true;
            }
        }
        if (!deferred) {
            float m = v[0];
            float ex[TOPK];
            float s = 0.0f;
            #pragma unroll
            for (int j = 0; j < TOPK; ++j) { ex[j] = expf(v[j] - m); s += ex[j]; }
            float inv = 1.0f / s;
            size_t base = (size_t)(t0 + t) * TOPK;
            #pragma unroll
            for (int j = 0; j < TOPK; ++j) {
                out_idx_f[base + j] = (float)id[j];
                out_gate[base + j]  = ex[j] * inv;
            }
        }
    }
}

// ---------- pass 2: fp64 exact recompute, coalesced (unchanged) -------------
__global__ __launch_bounds__(256) void moe_gate_refine(
    const float* __restrict__ hs,
    const float* __restrict__ w,
    float* __restrict__ out_idx_f,
    float* __restrict__ out_gate,
    const int* __restrict__ flag_cnt,
    const int* __restrict__ flag_list,
    int flag_cap)
{
    __shared__ float  hrow[HID];
    __shared__ double lgw[4][NEXP];
    __shared__ double lgd[NEXP];
    const int tid  = threadIdx.x;
    const int lane = tid & 63;
    const int wv   = tid >> 6;

    int n = flag_cnt[0];
    if (n > flag_cap) n = flag_cap;

    for (int fi = blockIdx.x; fi < n; fi += gridDim.x) {
        const int t = flag_list[fi];
        #pragma unroll
        for (int i = 0; i < 4; ++i)
            ((f32x4*)hrow)[tid + 256 * i] =
                ((const f32x4*)(hs + (size_t)t * HID))[tid + 256 * i];
        __syncthreads();

        for (int e = 0; e < NEXP; ++e) {
            const f32x4* wp = (const f32x4*)(w + (size_t)e * HID);
            double s0 = 0.0, s1 = 0.0, s2 = 0.0, s3 = 0.0;
            #pragma unroll
            for (int i = 0; i < 4; ++i) {
                f32x4 wf = wp[tid + 256 * i];
                f32x4 af = ((const f32x4*)hrow)[tid + 256 * i];
                s0 = fma((double)wf[0], (double)af[0], s0);
                s1 = fma((double)wf[1], (double)af[1], s1);
                s2 = fma((double)wf[2], (double)af[2], s2);
                s3 = fma((double)wf[3], (double)af[3], s3);
            }
            double d = (s0 + s1) + (s2 + s3);
            #pragma unroll
            for (int off = 32; off > 0; off >>= 1)
                d += __shfl_down(d, off, 64);
            if (lane == 0) lgw[wv][e] = d;
        }
        __syncthreads();
        if (tid < NEXP)
            lgd[tid] = (lgw[0][tid] + lgw[1][tid]) + (lgw[2][tid] + lgw[3][tid]);
        __syncthreads();

        if (tid == 0) {
            double v[TOPK];
            int    id[TOPK];
            #pragma unroll
            for (int j = 0; j < TOPK; ++j) { v[j] = -INFINITY; id[j] = -1; }
            for (int e = 0; e < NEXP; ++e) {
                double x = lgd[e];
                if (x > v[TOPK - 1]) {
                    int p = TOPK - 1;
                    while (p > 0 && v[p - 1] < x) {
                        v[p]  = v[p - 1];
                        id[p] = id[p - 1];
                        --p;
                    }
                    v[p]  = x;
                    id[p] = e;
                }
            }
            double m = v[0];
            double ex[TOPK];
            double s = 0.0;
            #pragma unroll
            for (int j = 0; j < TOPK; ++j) { ex[j] = exp(v[j] - m); s += ex[j]; }
            double inv = 1.0 / s;
            size_t base = (size_t)t * TOPK;
            #pragma unroll
            for (int j = 0; j < TOPK; ++j) {
                out_idx_f[base + j] = (float)id[j];
                out_gate[base + j]  = (float)(ex[j] * inv);
            }
        }
        __syncthreads();
    }
}

extern "C" void kernel_launch(void* const* d_in, const int* in_sizes, int n_in,
                              void* d_out, int out_size, void* d_ws, size_t ws_size,
                              hipStream_t stream) {
    const float* hs = (const float*)d_in[0];
    const float* w  = (const float*)d_in[1];
    float* out      = (float*)d_out;
    float* out_idx  = out;
    float* out_gate = out + (size_t)TOKENS * TOPK;

    // ws layout: whi[64*4096] u16 | wlo[64*4096] u16 | flag_cnt | flag_list
    unsigned short* whi = (unsigned short*)d_ws;
    unsigned short* wlo = whi + (size_t)NEXP * HID;
    int* flag_cnt  = (int*)(wlo + (size_t)NEXP * HID);
    int* flag_list = flag_cnt + 1;
    long flag_cap_l = ((long)ws_size - 2L * NEXP * HID * 2 - 16) / 4;
    int flag_cap = flag_cap_l < 0 ? 0 : (flag_cap_l > TOKENS ? TOKENS : (int)flag_cap_l);

    hipLaunchKernelGGL(prep_kernel, dim3(NEXP * HID / (256 * 8)), dim3(256), 0, stream,
                       w, whi, wlo, flag_cnt);
    hipLaunchKernelGGL(moe_gate_pass1, dim3(TOKENS / 16), dim3(256), 0, stream,
                       hs, whi, wlo, out_idx, out_gate, flag_cnt, flag_list, flag_cap);
    hipLaunchKernelGGL(moe_gate_refine, dim3(REFINE_BLOCKS), dim3(256), 0, stream,
                       hs, w, out_idx, out_gate, flag_cnt, flag_list, flag_cap);
}

// Round 6
// 237.418 us; speedup vs baseline: 1.0516x; 1.0516x over previous
//
#include <hip/hip_runtime.h>
#include <math.h>

#define TOKENS 16384
#define HID    4096
#define NEXP   64
#define TOPK   8
#define BT     32               // tokens per block
#define BK     64               // fp32 k per LDS tile (256B per row)
#define NT     (HID / BK)       // 64 K-tiles
#define TAU    5e-4f            // 10x margin over 3-split logit error tails
#define REFINE_BLOCKS 1024

typedef short          bf16x8 __attribute__((ext_vector_type(8)));
typedef unsigned short u16x8  __attribute__((ext_vector_type(8)));
typedef float          f32x4  __attribute__((ext_vector_type(4)));

__device__ __forceinline__ unsigned short bf16_rtn(float x) {
    unsigned u = __builtin_bit_cast(unsigned, x);
    u += 0x7FFFu + ((u >> 16) & 1u);
    return (unsigned short)(u >> 16);
}

__device__ __forceinline__ void splitf(float x, unsigned short& h, unsigned short& l) {
    h = bf16_rtn(x);
    float hf = __builtin_bit_cast(float, (unsigned)h << 16);
    l = bf16_rtn(x - hf);
}

// ---------- prep: W fp32 -> bf16 hi/lo (validated r3/r5), zero flag counter --
__global__ __launch_bounds__(256) void prep_kernel(
    const float* __restrict__ w,
    unsigned short* __restrict__ whi,
    unsigned short* __restrict__ wlo,
    int* __restrict__ flag_cnt)
{
    if (blockIdx.x == 0 && threadIdx.x == 0) flag_cnt[0] = 0;
    int gid = blockIdx.x * 256 + threadIdx.x;
    const f32x4* wp = (const f32x4*)w;
    f32x4 v0 = wp[gid * 2 + 0];
    f32x4 v1 = wp[gid * 2 + 1];
    u16x8 h8, l8;
    #pragma unroll
    for (int j = 0; j < 8; ++j) {
        float x = (j < 4) ? v0[j] : v1[j - 4];
        unsigned short h, l;
        splitf(x, h, l);
        h8[j] = h; l8[j] = l;
    }
    *(u16x8*)(whi + (size_t)gid * 8) = h8;
    *(u16x8*)(wlo + (size_t)gid * 8) = l8;
}

// ---------- pass 1: DMA-staged fp32 A + reg B, 3-split MFMA, top-8 ----------
// A: global_load_lds(16B) into linear LDS, source pre-swizzled so that reads
//    at byte^((row&7)<<4) are <=2-way bank-conflict (free). Rule #21: source
//    permutation == read permutation (involution), LDS dest linear.
// B: preconverted bf16 hi/lo direct to registers (L2-resident, tiny).
// 2 blocks/CU (grid 512, 16KB LDS) cover each other's barrier drains (m97).
__global__ __launch_bounds__(256) void moe_gate_pass1(
    const float* __restrict__ hs,
    const unsigned short* __restrict__ whi,
    const unsigned short* __restrict__ wlo,
    float* __restrict__ out_idx_f,
    float* __restrict__ out_gate,
    int* __restrict__ flag_cnt,
    int* __restrict__ flag_list,
    int flag_cap)
{
    __shared__ char smem[16384];            // 2 x 8KB fp32 A-tile buffers

    const int tid  = threadIdx.x;
    const int lane = tid & 63;
    const int wv   = tid >> 6;              // 4 waves
    const int t0   = blockIdx.x * BT;
    const int h    = wv & 1;                // token half (16)
    const int e2   = wv >> 1;               // expert half (32)
    const int r16  = lane & 15;
    const int l4   = lane >> 4;

    // staging: wave wv owns rows [wv*8, wv*8+8); 2 issues x 1KB
    int srow[2], soff[2];
    #pragma unroll
    for (int i = 0; i < 2; ++i) {
        int row = wv * 8 + i * 4 + l4;
        srow[i] = row;
        soff[i] = (r16 * 4) ^ ((row & 7) << 2);   // pre-swizzled element offset
    }

    // B fragment pointers (validated layout: col=lane&15, k=(lane>>4)*8+j)
    const int col = e2 * 32 + r16;
    const unsigned short* bh0 = whi + (size_t)col * HID + l4 * 8;
    const unsigned short* bl0 = wlo + (size_t)col * HID + l4 * 8;

    // A-fragment read: token row for this lane, swizzle key
    const int trow = h * 16 + r16;
    const int swz  = (trow & 7) << 4;

    f32x4 acc[2];
    #pragma unroll
    for (int ni = 0; ni < 2; ++ni) { acc[ni][0]=0.f; acc[ni][1]=0.f; acc[ni][2]=0.f; acc[ni][3]=0.f; }

    auto STAGE = [&](int buf, int t) {
        char* base = smem + buf * 8192 + wv * 2048;
        #pragma unroll
        for (int i = 0; i < 2; ++i) {
            const float* g = hs + (size_t)(t0 + srow[i]) * HID + t * BK + soff[i];
            __builtin_amdgcn_global_load_lds(
                (const __attribute__((address_space(1))) void*)g,
                (__attribute__((address_space(3))) void*)(base + i * 1024),
                16, 0, 0);
        }
    };

    auto COMPUTE = [&](int buf, int t) {
        const char* bp = smem + buf * 8192;
        bf16x8 Bh[2][2], Bl[2][2];                    // [ni][kk]
        const size_t kb = (size_t)t * BK;
        #pragma unroll
        for (int ni = 0; ni < 2; ++ni)
            #pragma unroll
            for (int kk = 0; kk < 2; ++kk) {
                Bh[ni][kk] = *(const bf16x8*)(bh0 + ni * 16 * HID + kb + kk * 32);
                Bl[ni][kk] = *(const bf16x8*)(bl0 + ni * 16 * HID + kb + kk * 32);
            }
        #pragma unroll
        for (int kk = 0; kk < 2; ++kk) {
            int a0 = trow * 256 + (kk * 32 + l4 * 8) * 4;
            f32x4 f0 = *(const f32x4*)(bp + ((a0     ) ^ swz));
            f32x4 f1 = *(const f32x4*)(bp + ((a0 + 16) ^ swz));
            bf16x8 fah, fal;
            #pragma unroll
            for (int j = 0; j < 8; ++j) {
                float x = (j < 4) ? f0[j] : f1[j - 4];
                unsigned short hh, ll;
                splitf(x, hh, ll);
                fah[j] = (short)hh; fal[j] = (short)ll;
            }
            #pragma unroll
            for (int ni = 0; ni < 2; ++ni) {
                acc[ni] = __builtin_amdgcn_mfma_f32_16x16x32_bf16(fah, Bh[ni][kk], acc[ni], 0, 0, 0);
                acc[ni] = __builtin_amdgcn_mfma_f32_16x16x32_bf16(fah, Bl[ni][kk], acc[ni], 0, 0, 0);
                acc[ni] = __builtin_amdgcn_mfma_f32_16x16x32_bf16(fal, Bh[ni][kk], acc[ni], 0, 0, 0);
            }
        }
    };

    STAGE(0, 0);
    __syncthreads();                        // vmcnt(0) drain implied
    for (int t = 0; t < NT; ++t) {
        if (t + 1 < NT) STAGE((t + 1) & 1, t + 1);
        COMPUTE(t & 1, t);
        __syncthreads();
    }

    // ---- epilogue: logits -> LDS [32][68], then top-9 + gap + softmax ----
    float* lg = (float*)smem;
    #pragma unroll
    for (int ni = 0; ni < 2; ++ni)
        #pragma unroll
        for (int r = 0; r < 4; ++r)
            lg[(h * 16 + l4 * 4 + r) * 68 + e2 * 32 + ni * 16 + r16] = acc[ni][r];
    __syncthreads();

    if (tid < BT) {
        const int t = tid;
        float v[9];
        int   id[9];
        #pragma unroll
        for (int j = 0; j < 9; ++j) { v[j] = -INFINITY; id[j] = -1; }
        for (int e = 0; e < NEXP; ++e) {
            float x = lg[t * 68 + e];
            if (x > v[8]) {
                int p = 8;
                while (p > 0 && v[p - 1] < x) {
                    v[p]  = v[p - 1];
                    id[p] = id[p - 1];
                    --p;
                }
                v[p]  = x;
                id[p] = e;
            }
        }
        float g = v[0] - v[1];
        #pragma unroll
        for (int j = 1; j < 8; ++j) g = fminf(g, v[j] - v[j + 1]);

        bool deferred = false;
        if (g < TAU) {
            int slot = atomicAdd(flag_cnt, 1);
            if (slot < flag_cap) {
                flag_list[slot] = t0 + t;
                deferred = true;
            }
        }
        if (!deferred) {
            float m = v[0];
            float ex[TOPK];
            float s = 0.0f;
            #pragma unroll
            for (int j = 0; j < TOPK; ++j) { ex[j] = expf(v[j] - m); s += ex[j]; }
            float inv = 1.0f / s;
            size_t base = (size_t)(t0 + t) * TOPK;
            #pragma unroll
            for (int j = 0; j < TOPK; ++j) {
                out_idx_f[base + j] = (float)id[j];
                out_gate[base + j]  = ex[j] * inv;
            }
        }
    }
}

// ---------- pass 2: fp64 exact recompute, coalesced (validated) -------------
__global__ __launch_bounds__(256) void moe_gate_refine(
    const float* __restrict__ hs,
    const float* __restrict__ w,
    float* __restrict__ out_idx_f,
    float* __restrict__ out_gate,
    const int* __restrict__ flag_cnt,
    const int* __restrict__ flag_list,
    int flag_cap)
{
    __shared__ float  hrow[HID];
    __shared__ double lgw[4][NEXP];
    __shared__ double lgd[NEXP];
    const int tid  = threadIdx.x;
    const int lane = tid & 63;
    const int wv   = tid >> 6;

    int n = flag_cnt[0];
    if (n > flag_cap) n = flag_cap;

    for (int fi = blockIdx.x; fi < n; fi += gridDim.x) {
        const int t = flag_list[fi];
        #pragma unroll
        for (int i = 0; i < 4; ++i)
            ((f32x4*)hrow)[tid + 256 * i] =
                ((const f32x4*)(hs + (size_t)t * HID))[tid + 256 * i];
        __syncthreads();

        for (int e = 0; e < NEXP; ++e) {
            const f32x4* wp = (const f32x4*)(w + (size_t)e * HID);
            double s0 = 0.0, s1 = 0.0, s2 = 0.0, s3 = 0.0;
            #pragma unroll
            for (int i = 0; i < 4; ++i) {
                f32x4 wf = wp[tid + 256 * i];
                f32x4 af = ((const f32x4*)hrow)[tid + 256 * i];
                s0 = fma((double)wf[0], (double)af[0], s0);
                s1 = fma((double)wf[1], (double)af[1], s1);
                s2 = fma((double)wf[2], (double)af[2], s2);
                s3 = fma((double)wf[3], (double)af[3], s3);
            }
            double d = (s0 + s1) + (s2 + s3);
            #pragma unroll
            for (int off = 32; off > 0; off >>= 1)
                d += __shfl_down(d, off, 64);
            if (lane == 0) lgw[wv][e] = d;
        }
        __syncthreads();
        if (tid < NEXP)
            lgd[tid] = (lgw[0][tid] + lgw[1][tid]) + (lgw[2][tid] + lgw[3][tid]);
        __syncthreads();

        if (tid == 0) {
            double v[TOPK];
            int    id[TOPK];
            #pragma unroll
            for (int j = 0; j < TOPK; ++j) { v[j] = -INFINITY; id[j] = -1; }
            for (int e = 0; e < NEXP; ++e) {
                double x = lgd[e];
                if (x > v[TOPK - 1]) {
                    int p = TOPK - 1;
                    while (p > 0 && v[p - 1] < x) {
                        v[p]  = v[p - 1];
                        id[p] = id[p - 1];
                        --p;
                    }
                    v[p]  = x;
                    id[p] = e;
                }
            }
            double m = v[0];
            double ex[TOPK];
            double s = 0.0;
            #pragma unroll
            for (int j = 0; j < TOPK; ++j) { ex[j] = exp(v[j] - m); s += ex[j]; }
            double inv = 1.0 / s;
            size_t base = (size_t)t * TOPK;
            #pragma unroll
            for (int j = 0; j < TOPK; ++j) {
                out_idx_f[base + j] = (float)id[j];
                out_gate[base + j]  = (float)(ex[j] * inv);
            }
        }
        __syncthreads();
    }
}

extern "C" void kernel_launch(void* const* d_in, const int* in_sizes, int n_in,
                              void* d_out, int out_size, void* d_ws, size_t ws_size,
                              hipStream_t stream) {
    const float* hs = (const float*)d_in[0];
    const float* w  = (const float*)d_in[1];
    float* out      = (float*)d_out;
    float* out_idx  = out;
    float* out_gate = out + (size_t)TOKENS * TOPK;

    unsigned short* whi = (unsigned short*)d_ws;
    unsigned short* wlo = whi + (size_t)NEXP * HID;
    int* flag_cnt  = (int*)(wlo + (size_t)NEXP * HID);
    int* flag_list = flag_cnt + 1;
    long flag_cap_l = ((long)ws_size - 2L * NEXP * HID * 2 - 16) / 4;
    int flag_cap = flag_cap_l < 0 ? 0 : (flag_cap_l > TOKENS ? TOKENS : (int)flag_cap_l);

    hipLaunchKernelGGL(prep_kernel, dim3(NEXP * HID / (256 * 8)), dim3(256), 0, stream,
                       w, whi, wlo, flag_cnt);
    hipLaunchKernelGGL(moe_gate_pass1, dim3(TOKENS / BT), dim3(256), 0, stream,
                       hs, whi, wlo, out_idx, out_gate, flag_cnt, flag_list, flag_cap);
    hipLaunchKernelGGL(moe_gate_refine, dim3(REFINE_BLOCKS), dim3(256), 0, stream,
                       hs, w, out_idx, out_gate, flag_cnt, flag_list, flag_cap);
}